// Round 11
// baseline (48.211 us; speedup 1.0000x reference)
//
#include <hip/hip_runtime.h>
#include <math.h>

// WaveletLayerND: fused mexican-hat wavelet + grouped 3x3 conv (kernel 1),
// then 1x1 channel mix (kernel 2). B=4, O=I=32, H=W=128, fp32 throughout.
//
// Round 11: 2-channel interleave ON the tap-basis skeleton (r10). r9's
// 2-channel attempt failed because each channel carried a ds_bpermute chain
// + 18 v2f of psi-window state; tap basis has neither (halo combine moved to
// epilogue, 2 bperm x 8 rows total). Two independent load->psi->9x pk_fma
// streams per wave double issue density, overlap channel B's loads/params
// with channel A's compute, and halve channel-transition prologue stalls.
// Accumulators TL/TC/TR are SHARED (channel sum). Row validity is folded
// into the per-row mhc scalar. Natural VGPR; NO launch_bounds cap (r7).

#define RSTRIP 8   // output rows per wave

typedef float v2f __attribute__((ext_vector_type(2)));

static __device__ __forceinline__ v2f vfma(float w, v2f a, v2f c) {
  return __builtin_elementwise_fma(a, (v2f){w, w}, c);
}
static __device__ __forceinline__ float bperm(int addr, float v) {
  return __int_as_float(__builtin_amdgcn_ds_bpermute(addr, __float_as_int(v)));
}
// psi((x-t)/s) scaled by m (= MH_C * row_validity):  m*(u-1)*exp(-u/2)
static __device__ __forceinline__ v2f psi2(v2f xv, float rs, float trs, float m) {
  const float NHL2E = -0.72134752044448170f; // -0.5 * log2(e)
  const v2f sx = __builtin_elementwise_fma(xv, (v2f){rs, rs}, (v2f){-trs, -trs});
  const v2f u  = sx * sx;
  v2f e;
  e.x = __builtin_amdgcn_exp2f(u.x * NHL2E);
  e.y = __builtin_amdgcn_exp2f(u.y * NHL2E);
  return __builtin_elementwise_fma(u, (v2f){m, m}, (v2f){-m, -m}) * e;
}

#define LDROW(base, r) (*(const v2f*)((base) + (size_t)(min(max((r), 0), 127)) * 128))

__global__ __launch_bounds__(256) void wavelet_grouped_conv(
    const float* __restrict__ x,      // (B, I, H, W)
    const float* __restrict__ scale,  // (O*I)
    const float* __restrict__ trans,  // (O*I)
    const float* __restrict__ wconv,  // (O, I, 3, 3)
    float* __restrict__ y,            // (B, O, H, W) workspace
    float mhc)
{
  const int tid   = threadIdx.x;
  const int lane  = tid & 63;
  const int iq    = tid >> 6;          // 0..3: which i-quarter this wave owns
  const int strip = blockIdx.x;        // 0..15
  const int o     = blockIdx.y;        // 0..31
  const int b     = blockIdx.z;        // 0..3
  const int r0    = strip * RSTRIP;
  const int c0    = lane << 1;         // this thread's two columns

  // bpermute byte-addresses: lane-1 and lane+1 (mod 64) — epilogue only
  const int a_up = ((lane + 63) & 63) << 2;
  const int a_dn = ((lane +  1) & 63) << 2;
  const bool lane0  = (lane == 0);
  const bool lane63 = (lane == 63);

  // row validity folded into the psi prefactor (0 == the conv's zero pad)
  const float mhc_m1 = (r0 > 0)       ? mhc : 0.f;   // input row r0-1
  const float mhc_p8 = (r0 + 8 < 128) ? mhc : 0.f;   // input row r0+8

  // per-tap accumulators: out[c] = TL[c-1] + TC[c] + TR[c+1] (combined at end)
  v2f TL[RSTRIP], TC[RSTRIP], TR[RSTRIP];
#pragma unroll
  for (int r = 0; r < RSTRIP; ++r) {
    TL[r] = (v2f){0.f, 0.f}; TC[r] = (v2f){0.f, 0.f}; TR[r] = (v2f){0.f, 0.f};
  }

  const float* xb = x + (size_t)b * 32 * 128 * 128;

#pragma unroll 1
  for (int ii = 0; ii < 4; ++ii) {
    const int iA  = iq * 8 + ii * 2;            // wave-uniform
    const int oiA = __builtin_amdgcn_readfirstlane(o * 32 + iA);
    const int oiB = oiA + 1;
    const float rsA  = 1.0f / scale[oiA];
    const float trsA = trans[oiA] * rsA;
    const float rsB  = 1.0f / scale[oiB];
    const float trsB = trans[oiB] * rsB;
    const float* wpA = wconv + oiA * 9;
    const float A00 = wpA[0], A01 = wpA[1], A02 = wpA[2];
    const float A10 = wpA[3], A11 = wpA[4], A12 = wpA[5];
    const float A20 = wpA[6], A21 = wpA[7], A22 = wpA[8];
    const float* wpB = wconv + oiB * 9;
    const float B00 = wpB[0], B01 = wpB[1], B02 = wpB[2];
    const float B10 = wpB[3], B11 = wpB[4], B12 = wpB[5];
    const float B20 = wpB[6], B21 = wpB[7], B22 = wpB[8];
    const float* baseA = xb + (size_t)iA * 128 * 128 + c0;
    const float* baseB = baseA + 128 * 128;

    v2f xaA = LDROW(baseA, r0 - 1);   // row for j=0
    v2f xaB = LDROW(baseB, r0 - 1);
    v2f xbA = LDROW(baseA, r0);       // row for j=1
    v2f xbB = LDROW(baseB, r0);

#pragma unroll
    for (int j = 0; j < RSTRIP + 2; ++j) {
      const v2f xcA = LDROW(baseA, r0 + j + 1);   // lookahead-2 (clamped)
      const v2f xcB = LDROW(baseB, r0 + j + 1);
      const float mj = (j == 0) ? mhc_m1 : (j == RSTRIP + 1) ? mhc_p8 : mhc;
      const v2f pA = psi2(xaA, rsA, trsA, mj);
      const v2f pB = psi2(xaB, rsB, trsB, mj);

      // input row ir=r0+j-1 feeds out rows t=j (w0x), t=j-1 (w1x), t=j-2 (w2x)
      if (j <= RSTRIP - 1) {
        TL[j] = vfma(A00, pA, TL[j]);   TL[j] = vfma(B00, pB, TL[j]);
        TC[j] = vfma(A01, pA, TC[j]);   TC[j] = vfma(B01, pB, TC[j]);
        TR[j] = vfma(A02, pA, TR[j]);   TR[j] = vfma(B02, pB, TR[j]);
      }
      if (j >= 1 && j <= RSTRIP) {
        TL[j-1] = vfma(A10, pA, TL[j-1]);   TL[j-1] = vfma(B10, pB, TL[j-1]);
        TC[j-1] = vfma(A11, pA, TC[j-1]);   TC[j-1] = vfma(B11, pB, TC[j-1]);
        TR[j-1] = vfma(A12, pA, TR[j-1]);   TR[j-1] = vfma(B12, pB, TR[j-1]);
      }
      if (j >= 2) {
        TL[j-2] = vfma(A20, pA, TL[j-2]);   TL[j-2] = vfma(B20, pB, TL[j-2]);
        TC[j-2] = vfma(A21, pA, TC[j-2]);   TC[j-2] = vfma(B21, pB, TC[j-2]);
        TR[j-2] = vfma(A22, pA, TR[j-2]);   TR[j-2] = vfma(B22, pB, TR[j-2]);
      }
      xaA = xbA; xbA = xcA;
      xaB = xbB; xbB = xcB;
    }
  }

  // horizontal combine: out[c0]   = TL[c0-1] + TC[c0]   + TR[c0+1]
  //                     out[c0+1] = TL[c0]   + TC[c0+1] + TR[c0+2]
  v2f acc[RSTRIP];
#pragma unroll
  for (int r = 0; r < RSTRIP; ++r) {
    float pl = bperm(a_up, TL[r].y);
    float pr = bperm(a_dn, TR[r].x);
    if (lane0)  pl = 0.f;
    if (lane63) pr = 0.f;
    v2f v;
    v.x = pl      + TC[r].x + TR[r].y;
    v.y = TL[r].x + TC[r].y + pr;
    acc[r] = v;
  }

  // reduce the four i-quarters through LDS (lane-major; b64 2-way is free)
  __shared__ v2f red[3][RSTRIP][64];   // 12 KB
  if (iq != 0) {
#pragma unroll
    for (int r = 0; r < RSTRIP; ++r) red[iq - 1][r][lane] = acc[r];
  }
  __syncthreads();
  if (iq == 0) {
    float* yb = y + (((size_t)b * 32 + o) * 128 + r0) * 128 + c0;
#pragma unroll
    for (int r = 0; r < RSTRIP; ++r) {
      const v2f v = acc[r] + red[0][r][lane] + red[1][r][lane] + red[2][r][lane];
      *(v2f*)(yb + (size_t)r * 128) = v;
    }
  }
}

__global__ __launch_bounds__(256) void mix1x1(
    const float* __restrict__ y,    // (B, O, H*W)
    const float* __restrict__ fw,   // (O_out, O_in)
    float* __restrict__ out)        // (B, O, H*W)
{
  const int px = blockIdx.x * 256 + threadIdx.x;  // 0..16383
  const int b  = blockIdx.y;
  const float* yb = y + (size_t)b * 32 * 16384 + px;
  float v[32];
#pragma unroll
  for (int o = 0; o < 32; ++o) v[o] = yb[(size_t)o * 16384];
  float* ob = out + (size_t)b * 32 * 16384 + px;
#pragma unroll
  for (int p = 0; p < 32; ++p) {
    float a = 0.f;
#pragma unroll
    for (int o = 0; o < 32; ++o) a = fmaf(fw[p * 32 + o], v[o], a);
    ob[(size_t)p * 16384] = a;
  }
}

extern "C" void kernel_launch(void* const* d_in, const int* in_sizes, int n_in,
                              void* d_out, int out_size, void* d_ws, size_t ws_size,
                              hipStream_t stream) {
  const float* x     = (const float*)d_in[0];
  const float* scale = (const float*)d_in[1];
  const float* trans = (const float*)d_in[2];
  const float* wconv = (const float*)d_in[3];
  const float* fw    = (const float*)d_in[4];
  float* out = (float*)d_out;
  float* y   = (float*)d_ws;   // 4*32*128*128 floats = 8.39 MB

  const float mhc = (float)(2.0 / (sqrt(3.0) * pow(M_PI, 0.25)));

  dim3 g1(128 / RSTRIP, 32, 4);  // (strips, o, b) = 2048 blocks x 256 thr
  wavelet_grouped_conv<<<g1, 256, 0, stream>>>(x, scale, trans, wconv, y, mhc);

  dim3 g2(16384 / 256, 4);       // (pixel tiles, b)
  mix1x1<<<g2, 256, 0, stream>>>(y, fw, out);
}